// Round 15
// baseline (433.632 us; speedup 1.0000x reference)
//
#include <hip/hip_runtime.h>

typedef unsigned short u16;
typedef unsigned int u32;
typedef __bf16 bf16x8 __attribute__((ext_vector_type(8)));
typedef float f32x4 __attribute__((ext_vector_type(4)));

#define T_DIM 256
#define U_DIM 64
#define DJ 640
#define VOCAB 1024

typedef __attribute__((address_space(3))) u32 lds_u32;
typedef const __attribute__((address_space(1))) u32 glb_u32;

__device__ __forceinline__ u16 f2bf(float f) {
    u32 x = __float_as_uint(f);
    x += 0x7fffu + ((x >> 16) & 1u);
    return (u16)(x >> 16);
}

__device__ __forceinline__ float fast_tanh(float x) {
    float e = __expf(2.0f * x);
    return 1.0f - 2.0f / (e + 1.0f);
}

// Fused prep (one dispatch, 128 threads/block, block-uniform branch):
//   blocks 0..1279    : enc projection
//   blocks 1280..1599 : pred projection
//   blocks 1600..2239 : W_out -> Wt bf16 transpose
__global__ __launch_bounds__(128) void prep_kernel(const float* __restrict__ enc,
                                                   const float* __restrict__ W_enc,
                                                   const float* __restrict__ b_enc,
                                                   const float* __restrict__ pred,
                                                   const float* __restrict__ W_pred,
                                                   const float* __restrict__ b_pred,
                                                   const float* __restrict__ W_out,
                                                   float* __restrict__ enc_proj,
                                                   float* __restrict__ pred_proj,
                                                   u16* __restrict__ Wt) {
    __shared__ float smem[4 * 640];
    int b = blockIdx.x;
    int tid = threadIdx.x;

    if (b < 1600) {
        const float* X; const float* W; const float* bias; float* out; int K, r0, jj;
        if (b < 1280) {
            X = enc;  W = W_enc;  bias = b_enc;  out = enc_proj;  K = 512;
            r0 = (b & 255) * 4;  jj = (b >> 8) * 128 + tid;
        } else {
            int b2 = b - 1280;
            X = pred; W = W_pred; bias = b_pred; out = pred_proj; K = 640;
            r0 = (b2 & 63) * 4;  jj = (b2 >> 6) * 128 + tid;
        }
        float* xs = smem;
        for (int idx = tid; idx < 4 * K; idx += 128) {
            int r = idx / K, k = idx - r * K;
            xs[r * K + k] = X[(size_t)(r0 + r) * K + k];
        }
        __syncthreads();
        float bb = bias[jj];
        float a0 = bb, a1 = bb, a2 = bb, a3 = bb;
#pragma unroll 8
        for (int k = 0; k < K; k++) {
            float w = W[(size_t)k * DJ + jj];
            a0 = fmaf(xs[k], w, a0);
            a1 = fmaf(xs[K + k], w, a1);
            a2 = fmaf(xs[2 * K + k], w, a2);
            a3 = fmaf(xs[3 * K + k], w, a3);
        }
        out[(size_t)(r0 + 0) * DJ + jj] = a0;
        out[(size_t)(r0 + 1) * DJ + jj] = a1;
        out[(size_t)(r0 + 2) * DJ + jj] = a2;
        out[(size_t)(r0 + 3) * DJ + jj] = a3;
    } else {
        float (*tile)[33] = (float(*)[33])smem;
        int b3 = b - 1600;
        int n0 = (b3 & 31) * 32, k0 = (b3 >> 5) * 32;
        int tx = tid & 31, ty4 = tid >> 5;
#pragma unroll
        for (int j = 0; j < 8; j++)
            tile[ty4 + j * 4][tx] = W_out[(size_t)(k0 + ty4 + j * 4) * VOCAB + n0 + tx];
        __syncthreads();
#pragma unroll
        for (int j = 0; j < 8; j++)
            Wt[(size_t)(n0 + ty4 + j * 4) * DJ + k0 + tx] = f2bf(tile[tx][ty4 + j * 4]);
    }
}

// A[m][k] = bf16(tanh(encp + predp)), 8 elems/thread
__global__ __launch_bounds__(256) void tanh_kernel(const float* __restrict__ encp,
                                                   const float* __restrict__ predp,
                                                   u16* __restrict__ A) {
    int id = blockIdx.x * 256 + threadIdx.x;
    int m = id / 80;
    int c = id - m * 80;
    int koff = c * 8;
    int b = m >> 14, t = (m >> 6) & 255, u = m & 63;
    const float4* pe = (const float4*)(encp + (size_t)(b * T_DIM + t) * DJ + koff);
    const float4* pp = (const float4*)(predp + (size_t)(b * U_DIM + u) * DJ + koff);
    float4 e0 = pe[0], e1 = pe[1];
    float4 p0 = pp[0], p1 = pp[1];
    uint4 v;
    v.x = (u32)f2bf(fast_tanh(e0.x + p0.x)) | ((u32)f2bf(fast_tanh(e0.y + p0.y)) << 16);
    v.y = (u32)f2bf(fast_tanh(e0.z + p0.z)) | ((u32)f2bf(fast_tanh(e0.w + p0.w)) << 16);
    v.z = (u32)f2bf(fast_tanh(e1.x + p1.x)) | ((u32)f2bf(fast_tanh(e1.y + p1.y)) << 16);
    v.w = (u32)f2bf(fast_tanh(e1.z + p1.z)) | ((u32)f2bf(fast_tanh(e1.w + p1.w)) << 16);
    *(uint4*)(A + (size_t)id * 8) = v;
}

// 8-phase 256x256 bf16 GEMM (T3+T4+T5): C[65536x1024] = A*Wt^T + bias, clamp.
// 512 thr (8 waves 2Mx4N), BK=64, LDS 128KB = [buf2][A/B][khalf2][256 rows x 32k u16].
// Per phase: {ds-read region batch | stage 1 half-tile (2 gload_lds)} barrier,
// setprio(1), 16 MFMA, setprio(0), counted vmcnt(6) only at ph4/ph8, barrier.
// Race-freedom: each phase's read batch ends with regs consumed by that phase's MFMA
// (lgkm wait drains the whole batch before the post-MFMA barrier); every re-stage is
// >=1 barrier pair after the region's last read. vmcnt ledger verified (see journal).
__global__ __launch_bounds__(512, 2) void gemm_kernel(const u16* __restrict__ A,
                                                      const u16* __restrict__ Wt,
                                                      const float* __restrict__ b_out,
                                                      float* __restrict__ out) {
    __shared__ u16 lds[2][2][2][8192];   // 128 KB

    int bid = blockIdx.x;                 // 1024 blocks
    int swz = (bid & 7) * 128 + (bid >> 3);   // XCD swizzle, bijective (1024%8==0)
    int ntile = swz & 3;
    int mtile = swz >> 2;
    int row0 = mtile * 256;
    int n0 = ntile * 256;

    int tid = threadIdx.x;
    int lane = tid & 63;
    int wave = tid >> 6;
    int wm = wave & 1;        // M-half owner
    int wn_ = wave >> 1;      // N-quarter owner (0..3)
    int lm = lane & 15;
    int quad = lane >> 4;

    // staging: one half-tile (region) = 256 rows x 32k x 2B = 16KB; slot sidx = tid+j*512
    // covers (row = sidx>>2, slot = sidx&3); slot s of row r holds global chunk s^(r&3).
    auto stage = [&](int buf, int mat, int kt, int kh) {
#pragma unroll
        for (int j = 0; j < 2; j++) {
            int sidx = tid + j * 512;
            int r = sidx >> 2;
            int c = (sidx & 3) ^ (r & 3);
            const u16* src = mat ? (Wt + (size_t)(n0 + r) * DJ)
                                 : (A + (size_t)(row0 + r) * DJ);
            __builtin_amdgcn_global_load_lds(
                (glb_u32*)(src + kt * 64 + kh * 32 + c * 8),
                (lds_u32*)(&lds[buf][mat][kh][(wave * 64 + j * 512) * 8]), 16, 0, 0);
        }
    };
    // fragment reads: reader wants chunk=quad -> slot quad^(row&3); row&3 == lm&3
    auto rdA = [&](int buf, int kh, int f) -> bf16x8 {
        int row = wm * 128 + f * 16 + lm;
        return *(const bf16x8*)(&lds[buf][0][kh][row * 32 + ((quad ^ (lm & 3)) * 8)]);
    };
    auto rdB = [&](int buf, int kh, int g) -> bf16x8 {
        int row = wn_ * 64 + g * 16 + lm;
        return *(const bf16x8*)(&lds[buf][1][kh][row * 32 + ((quad ^ (lm & 3)) * 8)]);
    };

    f32x4 acc[8][4];
#pragma unroll
    for (int m = 0; m < 8; m++)
#pragma unroll
        for (int n = 0; n < 4; n++) {
            acc[m][n][0] = 0.f; acc[m][n][1] = 0.f;
            acc[m][n][2] = 0.f; acc[m][n][3] = 0.f;
        }

#define MFMA_QUAD(MLO, AF, BF)                                                        \
    _Pragma("unroll") for (int m = 0; m < 4; m++)                                     \
    _Pragma("unroll") for (int n = 0; n < 4; n++)                                     \
        acc[(MLO) + m][n] = __builtin_amdgcn_mfma_f32_16x16x32_bf16(                  \
            AF[(MLO) + m], BF[n], acc[(MLO) + m][n], 0, 0, 0);

    // prologue: t0 fully (4 halves) + t1's A.k0,B.k0,A.k1 (3 halves)
    stage(0, 0, 0, 0); stage(0, 1, 0, 0); stage(0, 0, 0, 1); stage(0, 1, 0, 1);
    stage(1, 0, 1, 0); stage(1, 1, 1, 0); stage(1, 0, 1, 1);
    asm volatile("s_waitcnt vmcnt(6)" ::: "memory");   // t0 landed; t1's 3 halves in flight
    __builtin_amdgcn_s_barrier();

    for (int i = 0; i < 5; ++i) {            // K-tiles 2i (buf0), 2i+1 (buf1)
        int t2 = 2 * i + 2, t3 = 2 * i + 3;
        bool more = (i < 4);
        bf16x8 a0[8], a1[8], b0[4], b1[4];

        // ph1: read A0.k0+B0.k0; stage buf1.B.k1 <- tile 2i+1
#pragma unroll
        for (int f = 0; f < 8; f++) a0[f] = rdA(0, 0, f);
#pragma unroll
        for (int g = 0; g < 4; g++) b0[g] = rdB(0, 0, g);
        stage(1, 1, 2 * i + 1, 1);
        __builtin_amdgcn_s_barrier();
        __builtin_amdgcn_s_setprio(1);
        MFMA_QUAD(0, a0, b0)
        __builtin_amdgcn_s_setprio(0);
        __builtin_amdgcn_s_barrier();

        // ph2: read A0.k1; stage buf0.A.k0 <- t2
#pragma unroll
        for (int f = 0; f < 8; f++) a1[f] = rdA(0, 1, f);
        if (more) stage(0, 0, t2, 0);
        __builtin_amdgcn_s_barrier();
        __builtin_amdgcn_s_setprio(1);
        MFMA_QUAD(4, a0, b0)
        __builtin_amdgcn_s_setprio(0);
        __builtin_amdgcn_s_barrier();

        // ph3: read B0.k1; stage buf0.B.k0 <- t2
#pragma unroll
        for (int g = 0; g < 4; g++) b1[g] = rdB(0, 1, g);
        if (more) stage(0, 1, t2, 0);
        __builtin_amdgcn_s_barrier();
        __builtin_amdgcn_s_setprio(1);
        MFMA_QUAD(0, a1, b1)
        __builtin_amdgcn_s_setprio(0);
        __builtin_amdgcn_s_barrier();

        // ph4: stage buf0.A.k1 <- t2; counted vmcnt before end barrier
        if (more) stage(0, 0, t2, 1);
        __builtin_amdgcn_s_barrier();
        __builtin_amdgcn_s_setprio(1);
        MFMA_QUAD(4, a1, b1)
        __builtin_amdgcn_s_setprio(0);
        if (more) { asm volatile("s_waitcnt vmcnt(6)" ::: "memory"); }
        else      { asm volatile("s_waitcnt vmcnt(0)" ::: "memory"); }
        __builtin_amdgcn_s_barrier();

        // ph5: read A1.k0+B1.k0; stage buf0.B.k1 <- t2
#pragma unroll
        for (int f = 0; f < 8; f++) a0[f] = rdA(1, 0, f);
#pragma unroll
        for (int g = 0; g < 4; g++) b0[g] = rdB(1, 0, g);
        if (more) stage(0, 1, t2, 1);
        __builtin_amdgcn_s_barrier();
        __builtin_amdgcn_s_setprio(1);
        MFMA_QUAD(0, a0, b0)
        __builtin_amdgcn_s_setprio(0);
        __builtin_amdgcn_s_barrier();

        // ph6: read A1.k1; stage buf1.A.k0 <- t3
#pragma unroll
        for (int f = 0; f < 8; f++) a1[f] = rdA(1, 1, f);
        if (more) stage(1, 0, t3, 0);
        __builtin_amdgcn_s_barrier();
        __builtin_amdgcn_s_setprio(1);
        MFMA_QUAD(4, a0, b0)
        __builtin_amdgcn_s_setprio(0);
        __builtin_amdgcn_s_barrier();

        // ph7: read B1.k1; stage buf1.B.k0 <- t3
#pragma unroll
        for (int g = 0; g < 4; g++) b1[g] = rdB(1, 1, g);
        if (more) stage(1, 1, t3, 0);
        __builtin_amdgcn_s_barrier();
        __builtin_amdgcn_s_setprio(1);
        MFMA_QUAD(0, a1, b1)
        __builtin_amdgcn_s_setprio(0);
        __builtin_amdgcn_s_barrier();

        // ph8: stage buf1.A.k1 <- t3; counted vmcnt
        if (more) stage(1, 0, t3, 1);
        __builtin_amdgcn_s_barrier();
        __builtin_amdgcn_s_setprio(1);
        MFMA_QUAD(4, a1, b1)
        __builtin_amdgcn_s_setprio(0);
        if (more) { asm volatile("s_waitcnt vmcnt(6)" ::: "memory"); }
        __builtin_amdgcn_s_barrier();
    }
#undef MFMA_QUAD

    // coalesced epilogue: 2 rounds x 128 rows via LDS (f32 cs[128][256] = 128KB)
    float* cs = (float*)lds;
#pragma unroll
    for (int rnd = 0; rnd < 2; rnd++) {
        __syncthreads();
        if (wm == rnd) {
#pragma unroll
            for (int m = 0; m < 8; m++)
#pragma unroll
                for (int j = 0; j < 4; j++)
#pragma unroll
                    for (int r = 0; r < 4; r++)
                        cs[(m * 16 + quad * 4 + r) * 256 + wn_ * 64 + j * 16 + lm] = acc[m][j][r];
        }
        __syncthreads();
#pragma unroll
        for (int p = 0; p < 16; p++) {
            int g = tid + p * 512;
            int rw = g >> 6;
            int c4 = (g & 63) * 4;
            f32x4 v = *(const f32x4*)(cs + rw * 256 + c4);
            f32x4 b4 = *(const f32x4*)(b_out + n0 + c4);
#pragma unroll
            for (int cc = 0; cc < 4; cc++) {
                float x = v[cc] + b4[cc];
                v[cc] = fminf(fmaxf(x, -15.0f), 15.0f);
            }
            *(f32x4*)(out + (size_t)(row0 + rnd * 128 + rw) * VOCAB + n0 + c4) = v;
        }
    }
}

// ---------------- fallback (round-1 fused kernel) if ws too small ----------------
#define LDA 40
__global__ __launch_bounds__(256) void joint_fused(const float* __restrict__ encp,
                                                   const float* __restrict__ predp,
                                                   const u16* __restrict__ Wt,
                                                   const float* __restrict__ b_out,
                                                   float* __restrict__ out) {
    __shared__ u16 As[128 * LDA];
    __shared__ u16 Bs[128 * LDA];
    int ntile = blockIdx.x & 7;
    int mtile = blockIdx.x >> 3;
    int row0 = mtile * 128;
    int bidx = row0 >> 14;
    int t0 = (row0 & 16383) >> 6;
    int n0 = ntile * 128;
    int tid = threadIdx.x, lane = tid & 63, wave = tid >> 6;
    int wm = wave & 1, wn = wave >> 1, lm = lane & 15, quad = lane >> 4;
    int am = tid >> 1, ak = (tid & 1) << 4;
    const float* encA = encp + (size_t)(bidx * T_DIM + t0 + (am >> 6)) * DJ + ak;
    const float* predA = predp + (size_t)(bidx * U_DIM + (am & 63)) * DJ + ak;
    u16* Asw = As + am * LDA + ak;
    int bn = tid >> 1, bk = (tid & 1) << 4;
    const u16* WtB = Wt + (size_t)(n0 + bn) * DJ + bk;
    u16* Bsw = Bs + bn * LDA + bk;
    f32x4 acc[4][4];
#pragma unroll
    for (int i = 0; i < 4; i++)
#pragma unroll
        for (int j = 0; j < 4; j++) {
            acc[i][j][0] = 0.f; acc[i][j][1] = 0.f; acc[i][j][2] = 0.f; acc[i][j][3] = 0.f;
        }
    for (int k0 = 0; k0 < DJ; k0 += 32) {
        const float4* pe = (const float4*)(encA + k0);
        const float4* pp = (const float4*)(predA + k0);
#pragma unroll
        for (int i = 0; i < 4; i++) {
            float4 e = pe[i]; float4 p = pp[i];
            uint2 v;
            v.x = (u32)f2bf(fast_tanh(e.x + p.x)) | ((u32)f2bf(fast_tanh(e.y + p.y)) << 16);
            v.y = (u32)f2bf(fast_tanh(e.z + p.z)) | ((u32)f2bf(fast_tanh(e.w + p.w)) << 16);
            *(uint2*)(Asw + i * 4) = v;
        }
        const u16* src = WtB + k0;
        uint4 w0 = *(const uint4*)src;
        uint4 w1 = *(const uint4*)(src + 8);
        *(uint4*)Bsw = w0;
        *(uint4*)(Bsw + 8) = w1;
        __syncthreads();
        bf16x8 af[4], bfr[4];
#pragma unroll
        for (int i = 0; i < 4; i++)
            af[i] = *(const bf16x8*)(As + (wm * 64 + i * 16 + lm) * LDA + quad * 8);
#pragma unroll
        for (int j = 0; j < 4; j++)
            bfr[j] = *(const bf16x8*)(Bs + (wn * 64 + j * 16 + lm) * LDA + quad * 8);
#pragma unroll
        for (int i = 0; i < 4; i++)
#pragma unroll
            for (int j = 0; j < 4; j++)
                acc[i][j] = __builtin_amdgcn_mfma_f32_16x16x32_bf16(af[i], bfr[j], acc[i][j], 0, 0, 0);
        __syncthreads();
    }
#pragma unroll
    for (int j = 0; j < 4; j++) {
        int gc = n0 + wn * 64 + j * 16 + lm;
        float bo = b_out[gc];
#pragma unroll
        for (int i = 0; i < 4; i++) {
            int gr = row0 + wm * 64 + i * 16 + quad * 4;
#pragma unroll
            for (int r = 0; r < 4; r++) {
                float v = acc[i][j][r] + bo;
                v = fminf(fmaxf(v, -15.0f), 15.0f);
                out[(size_t)(gr + r) * VOCAB + gc] = v;
            }
        }
    }
}

extern "C" void kernel_launch(void* const* d_in, const int* in_sizes, int n_in,
                              void* d_out, int out_size, void* d_ws, size_t ws_size,
                              hipStream_t stream) {
    const float* enc    = (const float*)d_in[0];
    const float* pred   = (const float*)d_in[1];
    const float* W_enc  = (const float*)d_in[2];
    const float* b_enc  = (const float*)d_in[3];
    const float* W_pred = (const float*)d_in[4];
    const float* b_pred = (const float*)d_in[5];
    const float* W_out  = (const float*)d_in[6];
    const float* b_out  = (const float*)d_in[7];
    float* out = (float*)d_out;

    float* enc_proj  = (float*)d_ws;                     // 1024*640 f32
    float* pred_proj = enc_proj + 1024 * DJ;             // 256*640 f32
    u16*   Wt        = (u16*)(pred_proj + 256 * DJ);     // 1024*640 bf16
    u16*   Abuf      = Wt + 1024 * DJ;                   // 65536*640 bf16

    size_t need = (size_t)(1024 + 256) * DJ * 4 + (size_t)1024 * DJ * 2
                + (size_t)65536 * DJ * 2;

    prep_kernel<<<dim3(2240), dim3(128), 0, stream>>>(enc, W_enc, b_enc,
                                                      pred, W_pred, b_pred,
                                                      W_out, enc_proj, pred_proj, Wt);

    if (ws_size >= need) {
        tanh_kernel<<<dim3(65536 * 80 / 256), dim3(256), 0, stream>>>(enc_proj, pred_proj, Abuf);
        gemm_kernel<<<dim3(1024), dim3(512), 0, stream>>>(Abuf, Wt, b_out, out);
    } else {
        joint_fused<<<dim3(4096), dim3(256), 0, stream>>>(enc_proj, pred_proj, Wt, b_out, out);
    }
}